// Round 19
// baseline (258.989 us; speedup 1.0000x reference)
//
#include <hip/hip_runtime.h>
#include <hip/hip_bf16.h>
#include <stdint.h>

#define TOKENS 8192
#define NOUT   4096
#define KIN    4096

#define BM 256
#define BN 256
#define BK 32
#define NT (KIN / BK)   // 128 K-tiles

typedef __attribute__((ext_vector_type(8))) short bf16x8;
typedef __attribute__((ext_vector_type(4))) float f32x4;

__device__ __forceinline__ uint32_t rotl32(uint32_t x, int r) {
  return (x << r) | (x >> (32 - r));
}

__device__ __forceinline__ uint16_t f2bf_rne(float f) {
  uint32_t u = __float_as_uint(f);
  u += 0x7FFFu + ((u >> 16) & 1u);
  return (uint16_t)(u >> 16);
}

// Threefry-2x32, 20 rounds — JAX PRNG core.
__device__ __forceinline__ void threefry2x32(uint32_t k0, uint32_t k1,
                                             uint32_t c0, uint32_t c1,
                                             uint32_t& o0, uint32_t& o1) {
  uint32_t ks2 = 0x1BD11BDAu ^ k0 ^ k1;
  uint32_t x0 = c0 + k0;
  uint32_t x1 = c1 + k1;
#define TFR(r) { x0 += x1; x1 = rotl32(x1, (r)); x1 ^= x0; }
  TFR(13) TFR(15) TFR(26) TFR(6)
  x0 += k1;  x1 += ks2 + 1u;
  TFR(17) TFR(29) TFR(16) TFR(24)
  x0 += ks2; x1 += k0 + 2u;
  TFR(13) TFR(15) TFR(26) TFR(6)
  x0 += k0;  x1 += k1 + 3u;
  TFR(17) TFR(29) TFR(16) TFR(24)
  x0 += k1;  x1 += ks2 + 4u;
  TFR(13) TFR(15) TFR(26) TFR(6)
  x0 += ks2; x1 += k0 + 5u;
#undef TFR
  o0 = x0; o1 = x1;
}

// Fused prep, interleaved 4:1 hydrate:convert (r13, verified win).
__global__ void prep_kernel(const float* __restrict__ x,
                            uint16_t* __restrict__ xb,
                            uint16_t* __restrict__ W,
                            const int* __restrict__ seed_ptr) {
  uint32_t b = blockIdx.x;
  uint32_t g = b / 5u, r = b % 5u;
  if (r < 4u) {
    uint32_t k1 = (uint32_t)(*seed_ptr);                  // key = (0, seed)
    uint32_t j = (g * 4u + r) * 256u + threadIdx.x;       // 0 .. 2^24-1
    uint32_t o0, o1;
    threefry2x32(0u, k1, 0u, j, o0, o1);
    uint32_t bits = o0 ^ o1;
    const float scale = 0.03125f;
    const float mn    = -0.015625f;
    float f = __uint_as_float((bits >> 9) | 0x3F800000u) - 1.0f;
    float v = fmaxf(mn, f * scale + mn);
    W[j] = f2bf_rne(v);
  } else {
    uint32_t base = (g * 256u + threadIdx.x) * 8u;
    f32x4 a = *(const f32x4*)(x + base);
    f32x4 c = *(const f32x4*)(x + base + 4);
    union { uint16_t u[8]; bf16x8 v; } rr;
    rr.u[0] = f2bf_rne(a[0]); rr.u[1] = f2bf_rne(a[1]);
    rr.u[2] = f2bf_rne(a[2]); rr.u[3] = f2bf_rne(a[3]);
    rr.u[4] = f2bf_rne(c[0]); rr.u[5] = f2bf_rne(c[1]);
    rr.u[6] = f2bf_rne(c[2]); rr.u[7] = f2bf_rne(c[3]);
    *(bf16x8*)(xb + base) = rr.v;
  }
}

// ---------------------------------------------------------------------------
// ROUND 19: BK=32, 64 KiB LDS -> 2 blocks/CU. Same 256x256 tile, 8 waves,
// 16x16x32 MFMA, r13's 4-phase single-barrier ledger scaled to 4 loads/tile.
// Mechanism: co-resident blocks have independent barriers; while block A's
// waves convoy at a barrier (LDS-port phase), block B's waves run MFMA —
// overlapping the two pipes that a single block serializes (m114/m97).
//
// Per tile kt (buf = kt&1), quadrants (0,0),(0,1),(1,1),(1,0):
//   P1: read A0 (4) + B0 (2) | stage A1(kt+1)->buf^1 | barrier |
//       LKW(2) 4·MFMA | LKW(0) 4·MFMA
//   P2: read B1 (2) | stage A0(kt+2)->buf | barrier | LKW(1) 4 | LKW(0) 4
//   P3: read A1 (4, overwrites af) | stage B0(kt+2)->buf | barrier |
//       LKW(2) 4 | LKW(0) 4
//   P4: stage B1(kt+2)->buf | VMW(3) | barrier | 8·MFMA (cached af,bv0)
// RAW @VMW(3): in flight = kt-1's {A0,B0,B1(kt+1)} + kt's 4; keeping 3
// newest (= kt+2's A0,B0,B1) retires kt+1's A1 and everything older =>
// kt+1 fully landed; barrier publishes. WAR: single-barrier arrival
// implies the wave passed its previous LKW(0) => prior reads complete;
// stage slots have 2-phase lag. Prologue: 7 loads, VMW(3) => kt0's 4
// landed, THEN barrier (r16 race lesson).
// LDS layout: [buf][A|B][8192] u16; row = 64 B (32 k). Swizzle for 64B
// rows: read byte ^= ((fr>>1)&3)<<4; stage source pre-swizzle
// lsw = ((lane&3)^((lane>>3)&3))<<4 — same 8-slot/row-pair spread that
// measured 0 bank conflicts at 128B rows (r5-r18). gload_lds dest linear.
// Registers: 8 operand b128 (32 VGPR) + acc 128 — far under budget.
// ---------------------------------------------------------------------------
__global__ __launch_bounds__(512, 2)
void gemm_bias_kernel(const uint16_t* __restrict__ A,   // x  bf16 [TOKENS][KIN]
                      const uint16_t* __restrict__ B,   // W  bf16 [NOUT][KIN]
                      const float* __restrict__ bias,
                      float* __restrict__ C) {
  __shared__ uint16_t smem[2][2][8192];   // [buf][A=0/B=1][16KB] = 64 KiB

  const int nwgn = NOUT / BN;                 // 16
  const int nwg  = (TOKENS / BM) * nwgn;      // 512 (divisible by 8)
  int bid = blockIdx.x;
  int cpx = nwg >> 3;
  int swzb = (bid & 7) * cpx + (bid >> 3);    // bijective XCD swizzle
  const int tm = (swzb / nwgn) * BM;
  const int tn = (swzb % nwgn) * BN;

  const int t    = threadIdx.x;
  const int lane = t & 63;
  const int wid  = t >> 6;       // 0..7
  const int wm   = wid >> 2;     // 0..1
  const int wn   = wid & 3;      // 0..3
  const int fr   = lane & 15;
  const int fq   = lane >> 4;    // 0..3 (k-slot, 16B each of the 64B row)

  const int swzRd = ((fr >> 1) & 3) << 4;               // read byte XOR (64B rows)
  const int lsw   = (((lane & 3) ^ ((lane >> 3) & 3))) << 4;  // stage src swizzle

  // stage source pointers: thread covers row wid*16 + (lane>>2) of a half
  const char* sA  = (const char*)(A + (size_t)(tm + wid * 16 + (lane >> 2)) * KIN) + lsw;
  const char* sB  = (const char*)(B + (size_t)(tn + wid * 16 + (lane >> 2)) * KIN) + lsw;
  const char* sA1 = sA + (size_t)128 * KIN * 2;   // +128 rows (half 1)
  const char* sB1 = sB + (size_t)128 * KIN * 2;

  char* const smemB = (char*)&smem[0][0][0];
  char* const dstB  = smemB + wid * 1024 + lane * 16;   // linear dest in a half

  // ds_read byte-bases (relative to smemB); af[i] = base + MH*8192 + i*1024
  const int rA0 = (wm * 64 + fr) * 64 + ((fq << 4) ^ swzRd);           // A buf0
  const int rB0 = 16384 + (wn * 32 + fr) * 64 + ((fq << 4) ^ swzRd);   // B buf0

  f32x4 acc[8][4] = {};
  bf16x8 af[4], bv0[2], bv1[2];

  auto stage1 = [&](const char* src, char* dst) {
    __builtin_amdgcn_global_load_lds(
        (const __attribute__((address_space(1))) void*)src,
        (__attribute__((address_space(3))) void*)dst, 16, 0, 0);
  };

#define VMW(N) asm volatile("s_waitcnt vmcnt(" #N ")" ::: "memory")
#define LKW(N) asm volatile("s_waitcnt lgkmcnt(" #N ")" ::: "memory")
#define SB0    __builtin_amdgcn_sched_barrier(0)
#define PRI(p) __builtin_amdgcn_s_setprio(p)

// one MFMA into acc[MH*4+i][NH*2+j]
#define MF1(MH, NH, I, J, BV)                                                  \
    acc[(MH) * 4 + (I)][(NH) * 2 + (J)] =                                      \
        __builtin_amdgcn_mfma_f32_16x16x32_bf16(                               \
            af[I], BV[J], acc[(MH) * 4 + (I)][(NH) * 2 + (J)], 0, 0, 0);

#define MF_I01(MH, NH, BV) MF1(MH, NH, 0, 0, BV) MF1(MH, NH, 0, 1, BV)         \
                           MF1(MH, NH, 1, 0, BV) MF1(MH, NH, 1, 1, BV)
#define MF_I23(MH, NH, BV) MF1(MH, NH, 2, 0, BV) MF1(MH, NH, 2, 1, BV)         \
                           MF1(MH, NH, 3, 0, BV) MF1(MH, NH, 3, 1, BV)
#define MF_J0(MH, NH, BV)  MF1(MH, NH, 0, 0, BV) MF1(MH, NH, 1, 0, BV)         \
                           MF1(MH, NH, 2, 0, BV) MF1(MH, NH, 3, 0, BV)
#define MF_J1(MH, NH, BV)  MF1(MH, NH, 0, 1, BV) MF1(MH, NH, 1, 1, BV)         \
                           MF1(MH, NH, 2, 1, BV) MF1(MH, NH, 3, 1, BV)
#define MF_ALL(MH, NH, BV) MF_I01(MH, NH, BV) MF_I23(MH, NH, BV)

  // OFF1 = byte k-offset of kt+1; OFF2 = kt+2 (relative to pointers).
  // MODE: 0 steady; 1 = tile NT-2 (stage A1(last) only, VMW(0)@P4); 2 = last.
#define KTILE(BUF, OFF1, OFF2, MODE)                                           \
  {                                                                            \
    const int aB = rA0 + (BUF) * 32768;                                        \
    const int bB = rB0 + (BUF) * 32768;                                        \
    /* P1: (0,0) — reads af(A0) 4 + bv0(B0) 2; stage A1(kt+1)->buf^1 */        \
    af[0] = *(const bf16x8*)(smemB + aB);                                      \
    af[1] = *(const bf16x8*)(smemB + aB + 1024);                               \
    bv0[0] = *(const bf16x8*)(smemB + bB);                                     \
    bv0[1] = *(const bf16x8*)(smemB + bB + 1024);                              \
    SB0;                                                                       \
    af[2] = *(const bf16x8*)(smemB + aB + 2048);                               \
    af[3] = *(const bf16x8*)(smemB + aB + 3072);                               \
    if ((MODE) <= 1) stage1(sA1 + (OFF1), dstB + ((BUF) ^ 1) * 32768 + 8192);  \
    __builtin_amdgcn_s_barrier();                                              \
    LKW(2); SB0; PRI(1); MF_I01(0, 0, bv0)                                     \
    LKW(0); SB0; MF_I23(0, 0, bv0) PRI(0);                                     \
    /* P2: (0,1) — reads bv1(B1) 2; stage A0(kt+2)->buf */                     \
    bv1[0] = *(const bf16x8*)(smemB + bB + 8192);                              \
    SB0;                                                                       \
    bv1[1] = *(const bf16x8*)(smemB + bB + 8192 + 1024);                       \
    if ((MODE) == 0) stage1(sA + (OFF2), dstB + (BUF) * 32768);                \
    __builtin_amdgcn_s_barrier();                                              \
    LKW(1); SB0; PRI(1); MF_J0(0, 1, bv1)                                      \
    LKW(0); SB0; MF_J1(0, 1, bv1) PRI(0);                                      \
    /* P3: (1,1) — reads af(A1) 4 (overwrite); stage B0(kt+2)->buf */          \
    af[0] = *(const bf16x8*)(smemB + aB + 8192);                               \
    af[1] = *(const bf16x8*)(smemB + aB + 8192 + 1024);                        \
    SB0;                                                                       \
    af[2] = *(const bf16x8*)(smemB + aB + 8192 + 2048);                        \
    af[3] = *(const bf16x8*)(smemB + aB + 8192 + 3072);                        \
    if ((MODE) == 0) stage1(sB + (OFF2), dstB + (BUF) * 32768 + 16384);        \
    __builtin_amdgcn_s_barrier();                                              \
    LKW(2); SB0; PRI(1); MF_I01(1, 1, bv1)                                     \
    LKW(0); SB0; MF_I23(1, 1, bv1) PRI(0);                                     \
    /* P4: (1,0) — cached af(A1), bv0(B0); stage B1(kt+2)->buf; vm wait */     \
    if ((MODE) == 0) stage1(sB1 + (OFF2), dstB + (BUF) * 32768 + 24576);       \
    if ((MODE) == 0) { VMW(3); } else if ((MODE) == 1) { VMW(0); }             \
    __builtin_amdgcn_s_barrier();                                              \
    SB0; PRI(1); MF_ALL(1, 0, bv0) PRI(0);                                     \
  }

  // Prologue: kt0 {A0,B0,A1,B1} -> buf0; kt1 {A0,B0,B1} -> buf1; VMW(3)
  // (7 outstanding -> 4 oldest = all of kt0 landed) THEN barrier (publish
  // before first P1 reads — r16 race lesson). A1(kt1) staged at tile0's P1.
  stage1(sA,        dstB);                    // A0 kt0
  stage1(sB,        dstB + 16384);            // B0 kt0
  stage1(sA1,       dstB + 8192);             // A1 kt0
  stage1(sB1,       dstB + 24576);            // B1 kt0
  stage1(sA  + 64,  dstB + 32768);            // A0 kt1
  stage1(sB  + 64,  dstB + 32768 + 16384);    // B0 kt1
  stage1(sB1 + 64,  dstB + 32768 + 24576);    // B1 kt1
  VMW(3);
  __builtin_amdgcn_s_barrier();

  for (int it = 0; it < (NT - 2) / 2; ++it) {   // tiles 0..125
    KTILE(0, 64, 128, 0)
    KTILE(1, 128, 192, 0)
    sA += 128; sB += 128; sA1 += 128; sB1 += 128;
  }
  KTILE(0, 64, 0, 1)   // tile 126: stage A1(127) only, drain
  KTILE(1, 0, 0, 2)    // tile 127

#undef KTILE
#undef MF_ALL
#undef MF_J1
#undef MF_J0
#undef MF_I23
#undef MF_I01
#undef MF1
#undef PRI
#undef SB0
#undef LKW
#undef VMW

  // Epilogue: D row = fq*4 + rr, col = fr (m89/m91-verified), fused bias.
#pragma unroll
  for (int nj = 0; nj < 4; ++nj) {
    const int nh = nj >> 1, j = nj & 1;
    const int col = tn + wn * 32 + nh * 128 + j * 16 + fr;
    const float bvs = bias[col];
#pragma unroll
    for (int mi = 0; mi < 8; ++mi) {
      const int mh = mi >> 2, i = mi & 3;
      const int row0 = tm + wm * 64 + mh * 128 + i * 16 + fq * 4;
#pragma unroll
      for (int rr = 0; rr < 4; ++rr)
        C[(size_t)(row0 + rr) * NOUT + col] = acc[mi][nj][rr] + bvs;
    }
  }
}

extern "C" void kernel_launch(void* const* d_in, const int* in_sizes, int n_in,
                              void* d_out, int out_size, void* d_ws, size_t ws_size,
                              hipStream_t stream) {
  const float* x    = (const float*)d_in[0];   // [8192][4096] fp32
  const float* bias = (const float*)d_in[1];   // [4096] fp32
  const int*   seed = (const int*)d_in[2];     // [1] int
  float* y = (float*)d_out;                    // [8192][4096] fp32

  // workspace: W bf16 (32 MB) | x bf16 (64 MB) — 96 MB, proven available
  uint16_t* Wb = (uint16_t*)d_ws;
  uint16_t* Xb = Wb + (size_t)NOUT * KIN;

  prep_kernel<<<81920, 256, 0, stream>>>(x, Xb, Wb, seed);

  const int grid = (TOKENS / BM) * (NOUT / BN);   // 512
  gemm_bias_kernel<<<grid, 512, 0, stream>>>(Xb, Wb, bias, y);
}

// Round 20
// 251.954 us; speedup vs baseline: 1.0279x; 1.0279x over previous
//
#include <hip/hip_runtime.h>
#include <hip/hip_bf16.h>
#include <stdint.h>

#define TOKENS 8192
#define NOUT   4096
#define KIN    4096

#define BM 256
#define BN 256
#define BK 64
#define NT (KIN / BK)   // 64 K-tiles

typedef __attribute__((ext_vector_type(8))) short bf16x8;
typedef __attribute__((ext_vector_type(4))) float f32x4;

__device__ __forceinline__ uint32_t rotl32(uint32_t x, int r) {
  return (x << r) | (x >> (32 - r));
}

__device__ __forceinline__ uint16_t f2bf_rne(float f) {
  uint32_t u = __float_as_uint(f);
  u += 0x7FFFu + ((u >> 16) & 1u);
  return (uint16_t)(u >> 16);
}

// Threefry-2x32, 20 rounds — JAX PRNG core.
__device__ __forceinline__ void threefry2x32(uint32_t k0, uint32_t k1,
                                             uint32_t c0, uint32_t c1,
                                             uint32_t& o0, uint32_t& o1) {
  uint32_t ks2 = 0x1BD11BDAu ^ k0 ^ k1;
  uint32_t x0 = c0 + k0;
  uint32_t x1 = c1 + k1;
#define TFR(r) { x0 += x1; x1 = rotl32(x1, (r)); x1 ^= x0; }
  TFR(13) TFR(15) TFR(26) TFR(6)
  x0 += k1;  x1 += ks2 + 1u;
  TFR(17) TFR(29) TFR(16) TFR(24)
  x0 += ks2; x1 += k0 + 2u;
  TFR(13) TFR(15) TFR(26) TFR(6)
  x0 += k0;  x1 += k1 + 3u;
  TFR(17) TFR(29) TFR(16) TFR(24)
  x0 += k1;  x1 += ks2 + 4u;
  TFR(13) TFR(15) TFR(26) TFR(6)
  x0 += ks2; x1 += k0 + 5u;
#undef TFR
  o0 = x0; o1 = x1;
}

// Fused prep, interleaved 4:1 hydrate:convert (r13, verified win).
__global__ void prep_kernel(const float* __restrict__ x,
                            uint16_t* __restrict__ xb,
                            uint16_t* __restrict__ W,
                            const int* __restrict__ seed_ptr) {
  uint32_t b = blockIdx.x;
  uint32_t g = b / 5u, r = b % 5u;
  if (r < 4u) {
    uint32_t k1 = (uint32_t)(*seed_ptr);                  // key = (0, seed)
    uint32_t j = (g * 4u + r) * 256u + threadIdx.x;       // 0 .. 2^24-1
    uint32_t o0, o1;
    threefry2x32(0u, k1, 0u, j, o0, o1);
    uint32_t bits = o0 ^ o1;
    const float scale = 0.03125f;
    const float mn    = -0.015625f;
    float f = __uint_as_float((bits >> 9) | 0x3F800000u) - 1.0f;
    float v = fmaxf(mn, f * scale + mn);
    W[j] = f2bf_rne(v);
  } else {
    uint32_t base = (g * 256u + threadIdx.x) * 8u;
    f32x4 a = *(const f32x4*)(x + base);
    f32x4 c = *(const f32x4*)(x + base + 4);
    union { uint16_t u[8]; bf16x8 v; } rr;
    rr.u[0] = f2bf_rne(a[0]); rr.u[1] = f2bf_rne(a[1]);
    rr.u[2] = f2bf_rne(a[2]); rr.u[3] = f2bf_rne(a[3]);
    rr.u[4] = f2bf_rne(c[0]); rr.u[5] = f2bf_rne(c[1]);
    rr.u[6] = f2bf_rne(c[2]); rr.u[7] = f2bf_rne(c[3]);
    *(bf16x8*)(xb + base) = rr.v;
  }
}

// ---------------------------------------------------------------------------
// r18 loop (verified, best family member: 4-phase single-barrier, addressing
// diet, pre-barrier counted lgkm) + ROUND 20: VECTORIZED EPILOGUE.
// After the K-loop, all cross-wave LDS reads are complete (each wave's last
// reads retire before the final P4 barrier; P4 MFMA is register-only), so
// LDS is reusable. Each wave transposes its output through a PRIVATE
// [32][36]-f32 LDS region (row stride 144 B -> 16B-aligned rows, <=2-way
// banks both phases) and stores dwordx4: 8 lanes cover 128 B contiguous
// per row, 8 rows per instruction — replacing 64 scalar dword stores.
// K-loop ledger unchanged (see r13/r17/r18 proofs).
// ---------------------------------------------------------------------------
__global__ __launch_bounds__(512, 2)
void gemm_bias_kernel(const uint16_t* __restrict__ A,   // x  bf16 [TOKENS][KIN]
                      const uint16_t* __restrict__ B,   // W  bf16 [NOUT][KIN]
                      const float* __restrict__ bias,
                      float* __restrict__ C) {
  __shared__ uint16_t smem[2][2][16384];   // [buf][A=0/B=1][32KB] = 128 KiB

  const int nwgn = NOUT / BN;                 // 16
  const int nwg  = (TOKENS / BM) * nwgn;      // 512 (divisible by 8)
  int bid = blockIdx.x;
  int cpx = nwg >> 3;
  int swzb = (bid & 7) * cpx + (bid >> 3);    // bijective XCD swizzle
  const int tm = (swzb / nwgn) * BM;
  const int tn = (swzb % nwgn) * BN;

  const int t    = threadIdx.x;
  const int lane = t & 63;
  const int wid  = t >> 6;       // 0..7
  const int wm   = wid >> 2;     // 0..1
  const int wn   = wid & 3;      // 0..3
  const int fr   = lane & 15;
  const int fq   = lane >> 4;

  const int swzRd = (lane & 7) << 4;                    // frag-read byte XOR
  const int lsw   = ((lane & 7) ^ (lane >> 3)) << 4;    // stage src byte offset

  // loop-carried stage source pointers (+256 B per 2-tile iteration)
  const char* sA  = (const char*)(A + (size_t)(tm + wid * 16 + (lane >> 3)) * KIN) + lsw;
  const char* sB  = (const char*)(B + (size_t)(tn + wid * 16 + (lane >> 3)) * KIN) + lsw;
  const char* sA1 = sA + (size_t)128 * KIN * 2;   // +128 rows (half 1)
  const char* sB1 = sB + (size_t)128 * KIN * 2;

  char* const smemB = (char*)&smem[0][0][0];
  char* const dstB  = smemB + wid * 2048 + lane * 16;

  // ds_read byte-bases (relative to smemB); s1 = s0 ^ 64 (exact)
  const int rA00 = (wm * 64 + fr) * 128 + ((fq << 4) ^ swzRd);  // A buf0 s0
  const int rA01 = rA00 ^ 64;
  const int rA10 = rA00 + 65536;
  const int rA11 = rA10 ^ 64;
  const int rB00 = 32768 + (wn * 32 + fr) * 128 + ((fq << 4) ^ swzRd);
  const int rB01 = rB00 ^ 64;
  const int rB10 = rB00 + 65536;
  const int rB11 = rB10 ^ 64;

  f32x4 acc[8][4] = {};
  bf16x8 af[2][4], bv0[2][2], bv1[2][2];

  auto stage2 = [&](const char* src, char* dst) {
    __builtin_amdgcn_global_load_lds(
        (const __attribute__((address_space(1))) void*)src,
        (__attribute__((address_space(3))) void*)dst, 16, 0, 0);
    __builtin_amdgcn_global_load_lds(
        (const __attribute__((address_space(1))) void*)(src + (size_t)8 * KIN * 2),
        (__attribute__((address_space(3))) void*)(dst + 1024), 16, 0, 0);
  };

#define VMW(N) asm volatile("s_waitcnt vmcnt(" #N ")" ::: "memory")
#define LKW(N) asm volatile("s_waitcnt lgkmcnt(" #N ")" ::: "memory")
#define SB0    __builtin_amdgcn_sched_barrier(0)
#define PRI(p) __builtin_amdgcn_s_setprio(p)

// 4 ds_read_b128: af[S][0..3] from base BASE (+ i*2048 immediates)
#define RD_A4(BASE, S)                                                         \
    _Pragma("unroll")                                                          \
    for (int i_ = 0; i_ < 4; ++i_)                                             \
      af[S][i_] = *(const bf16x8*)(smemB + (BASE) + i_ * 2048);

// 2 ds_read_b128: BV[S][0..1] from base BASE
#define RD_B2(BASE, BV, S)                                                     \
    _Pragma("unroll")                                                          \
    for (int j_ = 0; j_ < 2; ++j_)                                             \
      BV[S][j_] = *(const bf16x8*)(smemB + (BASE) + j_ * 2048);

// 8 MFMA: k-group S of quadrant (MH,NH)
#define MF8(MH, NH, BV, S)                                                     \
    _Pragma("unroll")                                                          \
    for (int i_ = 0; i_ < 4; ++i_)                                             \
      _Pragma("unroll")                                                        \
      for (int j_ = 0; j_ < 2; ++j_)                                           \
        acc[(MH) * 4 + i_][(NH) * 2 + j_] =                                    \
            __builtin_amdgcn_mfma_f32_16x16x32_bf16(                           \
                af[S][i_], BV[S][j_], acc[(MH) * 4 + i_][(NH) * 2 + j_],       \
                0, 0, 0);

  // OFF1 = byte k-offset of kt+1; OFF2 = kt+2 (relative to pointers).
  // MODE: 0 steady; 1 = kt62 (stage A1(63) only, VMW(0)@P4); 2 = kt63.
#define KTILE(BUF, OFF1, OFF2, MODE)                                           \
  {                                                                            \
    /* P1: reads A0 + B0 (s0 | s1), stage A1(kt+1)->buf^1 */                   \
    RD_A4((BUF) ? rA10 : rA00, 0) RD_B2((BUF) ? rB10 : rB00, bv0, 0)           \
    SB0;                                                                       \
    RD_A4((BUF) ? rA11 : rA01, 1) RD_B2((BUF) ? rB11 : rB01, bv0, 1)           \
    if ((MODE) <= 1) stage2(sA1 + (OFF1),                                      \
                            dstB + ((BUF) ^ 1) * 65536 + 16384);               \
    LKW(8);                                                                    \
    __builtin_amdgcn_s_barrier();                                              \
    LKW(6); SB0; PRI(1); MF8(0, 0, bv0, 0)                                     \
    LKW(0); SB0; MF8(0, 0, bv0, 1) PRI(0);                                     \
    /* P2: reads B1 (s0 | s1) */                                               \
    RD_B2(((BUF) ? rB10 : rB00) + 16384, bv1, 0)                               \
    SB0;                                                                       \
    RD_B2(((BUF) ? rB11 : rB01) + 16384, bv1, 1)                               \
    LKW(2);                                                                    \
    __builtin_amdgcn_s_barrier();                                              \
    LKW(2); SB0; PRI(1); MF8(0, 1, bv1, 0)                                     \
    LKW(0); SB0; MF8(0, 1, bv1, 1) PRI(0);                                     \
    /* P3: reads A1 (s0 | s1, overwrites af), stage A0+B0(kt+2)->buf */        \
    RD_A4(((BUF) ? rA10 : rA00) + 16384, 0)                                    \
    SB0;                                                                       \
    RD_A4(((BUF) ? rA11 : rA01) + 16384, 1)                                    \
    if ((MODE) == 0) { stage2(sA + (OFF2), dstB + (BUF) * 65536);              \
                       stage2(sB + (OFF2), dstB + (BUF) * 65536 + 32768); }    \
    LKW(4);                                                                    \
    __builtin_amdgcn_s_barrier();                                              \
    LKW(4); SB0; PRI(1); MF8(1, 1, bv1, 0)                                     \
    LKW(0); SB0; MF8(1, 1, bv1, 1) PRI(0);                                     \
    /* P4: stage B1(kt+2)->buf | the ONE vm wait | barrier | cached MFMA */    \
    if ((MODE) == 0) stage2(sB1 + (OFF2), dstB + (BUF) * 65536 + 49152);       \
    if ((MODE) == 0) { VMW(6); } else if ((MODE) == 1) { VMW(0); }             \
    __builtin_amdgcn_s_barrier();                                              \
    SB0; PRI(1); MF8(1, 0, bv0, 0) MF8(1, 0, bv0, 1) PRI(0);                   \
  }

  // Prologue: kt0 all 4 halves -> buf0, kt1's A0,B0,B1 -> buf1; VMW(6)
  // (14 outstanding -> the 8 oldest = all of kt0 landed) THEN s_barrier
  // to publish cross-wave BEFORE the first KTILE's P1 reads (r16 fix).
  stage2(sA,        dstB);                    // A0 kt0
  stage2(sB,        dstB + 32768);            // B0 kt0
  stage2(sA1,       dstB + 16384);            // A1 kt0
  stage2(sB1,       dstB + 49152);            // B1 kt0
  stage2(sA  + 128, dstB + 65536);            // A0 kt1
  stage2(sB  + 128, dstB + 65536 + 32768);    // B0 kt1
  stage2(sB1 + 128, dstB + 65536 + 49152);    // B1 kt1
  VMW(6);
  __builtin_amdgcn_s_barrier();

  for (int it = 0; it < (NT - 2) / 2; ++it) {   // tiles 0..61
    KTILE(0, 128, 256, 0)
    KTILE(1, 256, 384, 0)
    sA += 256; sB += 256; sA1 += 256; sB1 += 256;
  }
  KTILE(0, 128, 0, 1)   // kt62: stage A1(63) only, drain
  KTILE(1, 0, 0, 2)     // kt63

#undef KTILE
#undef MF8
#undef RD_B2
#undef RD_A4
#undef PRI
#undef SB0
#undef LKW
#undef VMW

  // ---- Vectorized epilogue (round 20) ----
  // All cross-wave LDS reads ended at the final P4 barrier (P4 MFMA is
  // register-only), so smem is reusable. Per-wave private region:
  // [32 rows][36 f32] = 4608 B (row stride 144 B: 16B-aligned rows,
  // <=2-way banks on write (fq-groups +16 banks) and read (+4/row)).
  // Mapping (m89/m91-verified): acc[mh*4+i][nh*2+j][rr] holds
  // C[tm+wm*64+mh*128+i*16+fq*4+rr][tn+wn*32+nh*128+j*16+fr].
  __builtin_amdgcn_s_barrier();
  float* const eb = (float*)(smemB + wid * 4608);
  const int erow = lane >> 3;          // 0..7
  const int ecol = (lane & 7) * 4;     // 0,4,...,28
#pragma unroll
  for (int mh = 0; mh < 2; ++mh) {
#pragma unroll
    for (int nh = 0; nh < 2; ++nh) {
#pragma unroll
      for (int c = 0; c < 2; ++c) {
        // stage 32x32 chunk (rows mh*128+c*32.., cols nh*128..) into LDS
#pragma unroll
        for (int i2 = 0; i2 < 2; ++i2)
#pragma unroll
          for (int j = 0; j < 2; ++j)
#pragma unroll
            for (int rr = 0; rr < 4; ++rr)
              eb[(i2 * 16 + fq * 4 + rr) * 36 + j * 16 + fr] =
                  acc[mh * 4 + c * 2 + i2][nh * 2 + j][rr] +
                  bias[tn + wn * 32 + nh * 128 + j * 16 + fr];
        __builtin_amdgcn_s_waitcnt(0);  // lgkm drain: writes before reads
        // coalesced read-back + dwordx4 stores: 8 rows x 128 B per instr
        const size_t rbase = (size_t)(tm + wm * 64 + mh * 128 + c * 32 + erow);
        float* cp = C + rbase * NOUT + tn + wn * 32 + nh * 128 + ecol;
#pragma unroll
        for (int rb = 0; rb < 4; ++rb) {
          f32x4 v = *(const f32x4*)(eb + (rb * 8 + erow) * 36 + ecol);
          *(f32x4*)(cp + (size_t)rb * 8 * NOUT) = v;
        }
        __builtin_amdgcn_s_waitcnt(0);  // reads retired before next overwrite
      }
    }
  }
}

extern "C" void kernel_launch(void* const* d_in, const int* in_sizes, int n_in,
                              void* d_out, int out_size, void* d_ws, size_t ws_size,
                              hipStream_t stream) {
  const float* x    = (const float*)d_in[0];   // [8192][4096] fp32
  const float* bias = (const float*)d_in[1];   // [4096] fp32
  const int*   seed = (const int*)d_in[2];     // [1] int
  float* y = (float*)d_out;                    // [8192][4096] fp32

  // workspace: W bf16 (32 MB) | x bf16 (64 MB) — 96 MB, proven available
  uint16_t* Wb = (uint16_t*)d_ws;
  uint16_t* Xb = Wb + (size_t)NOUT * KIN;

  prep_kernel<<<81920, 256, 0, stream>>>(x, Xb, Wb, seed);

  const int grid = (TOKENS / BM) * (NOUT / BN);   // 512
  gemm_bias_kernel<<<grid, 512, 0, stream>>>(Xb, Wb, bias, y);
}

// Round 21
// 249.503 us; speedup vs baseline: 1.0380x; 1.0098x over previous
//
#include <hip/hip_runtime.h>
#include <hip/hip_bf16.h>
#include <stdint.h>

#define TOKENS 8192
#define NOUT   4096
#define KIN    4096

#define BM 256
#define BN 256
#define BK 64
#define NT (KIN / BK)   // 64 K-tiles

typedef __attribute__((ext_vector_type(8))) short bf16x8;
typedef __attribute__((ext_vector_type(4))) float f32x4;

__device__ __forceinline__ uint32_t rotl32(uint32_t x, int r) {
  return (x << r) | (x >> (32 - r));
}

__device__ __forceinline__ uint16_t f2bf_rne(float f) {
  uint32_t u = __float_as_uint(f);
  u += 0x7FFFu + ((u >> 16) & 1u);
  return (uint16_t)(u >> 16);
}

// Threefry-2x32, 20 rounds — JAX PRNG core.
__device__ __forceinline__ void threefry2x32(uint32_t k0, uint32_t k1,
                                             uint32_t c0, uint32_t c1,
                                             uint32_t& o0, uint32_t& o1) {
  uint32_t ks2 = 0x1BD11BDAu ^ k0 ^ k1;
  uint32_t x0 = c0 + k0;
  uint32_t x1 = c1 + k1;
#define TFR(r) { x0 += x1; x1 = rotl32(x1, (r)); x1 ^= x0; }
  TFR(13) TFR(15) TFR(26) TFR(6)
  x0 += k1;  x1 += ks2 + 1u;
  TFR(17) TFR(29) TFR(16) TFR(24)
  x0 += ks2; x1 += k0 + 2u;
  TFR(13) TFR(15) TFR(26) TFR(6)
  x0 += k0;  x1 += k1 + 3u;
  TFR(17) TFR(29) TFR(16) TFR(24)
  x0 += k1;  x1 += ks2 + 4u;
  TFR(13) TFR(15) TFR(26) TFR(6)
  x0 += ks2; x1 += k0 + 5u;
#undef TFR
  o0 = x0; o1 = x1;
}

// ROUND 21 prep: hydrate packs 8 elements/thread (8 threefrys -> one 16B
// bf16x8 store: same VALU, 8x fewer stores, full coalescing — was 2B/thread).
// Interleave re-balanced to new block counts: 8192 hydrate : 16384 convert
// via b%3 (1:2). Hydration math VERIFIED round 3.
__global__ void prep_kernel(const float* __restrict__ x,
                            uint16_t* __restrict__ xb,
                            uint16_t* __restrict__ W,
                            const int* __restrict__ seed_ptr) {
  uint32_t b = blockIdx.x;
  uint32_t g = b / 3u, r = b % 3u;
  if (r == 0u) {
    // hydrate group g in [0, 8192): elements j0..j0+7
    uint32_t k1 = (uint32_t)(*seed_ptr);                  // key = (0, seed)
    uint32_t j0 = (g * 256u + threadIdx.x) * 8u;          // 0 .. 2^24-8
    const float scale = 0.03125f;
    const float mn    = -0.015625f;
    union { uint16_t u[8]; bf16x8 v; } rr;
#pragma unroll
    for (int e = 0; e < 8; ++e) {
      uint32_t o0, o1;
      threefry2x32(0u, k1, 0u, j0 + (uint32_t)e, o0, o1);
      uint32_t bits = o0 ^ o1;
      float f = __uint_as_float((bits >> 9) | 0x3F800000u) - 1.0f;
      float v = fmaxf(mn, f * scale + mn);
      rr.u[e] = f2bf_rne(v);
    }
    *(bf16x8*)(W + j0) = rr.v;
  } else {
    // convert group cg in [0, 16384): 8 fp32 -> 8 bf16
    uint32_t cg = g * 2u + (r - 1u);
    uint32_t base = (cg * 256u + threadIdx.x) * 8u;
    f32x4 a = *(const f32x4*)(x + base);
    f32x4 c = *(const f32x4*)(x + base + 4);
    union { uint16_t u[8]; bf16x8 v; } rr;
    rr.u[0] = f2bf_rne(a[0]); rr.u[1] = f2bf_rne(a[1]);
    rr.u[2] = f2bf_rne(a[2]); rr.u[3] = f2bf_rne(a[3]);
    rr.u[4] = f2bf_rne(c[0]); rr.u[5] = f2bf_rne(c[1]);
    rr.u[6] = f2bf_rne(c[2]); rr.u[7] = f2bf_rne(c[3]);
    *(bf16x8*)(xb + base) = rr.v;
  }
}

// ---------------------------------------------------------------------------
// GEMM: byte-identical to round 20 (verified best: 4-phase single-barrier
// schedule, addressing diet, pre-barrier counted lgkm, vectorized LDS-
// transpose epilogue). See r13/r17/r18/r20 proofs in comments below.
// ---------------------------------------------------------------------------
__global__ __launch_bounds__(512, 2)
void gemm_bias_kernel(const uint16_t* __restrict__ A,   // x  bf16 [TOKENS][KIN]
                      const uint16_t* __restrict__ B,   // W  bf16 [NOUT][KIN]
                      const float* __restrict__ bias,
                      float* __restrict__ C) {
  __shared__ uint16_t smem[2][2][16384];   // [buf][A=0/B=1][32KB] = 128 KiB

  const int nwgn = NOUT / BN;                 // 16
  const int nwg  = (TOKENS / BM) * nwgn;      // 512 (divisible by 8)
  int bid = blockIdx.x;
  int cpx = nwg >> 3;
  int swzb = (bid & 7) * cpx + (bid >> 3);    // bijective XCD swizzle
  const int tm = (swzb / nwgn) * BM;
  const int tn = (swzb % nwgn) * BN;

  const int t    = threadIdx.x;
  const int lane = t & 63;
  const int wid  = t >> 6;       // 0..7
  const int wm   = wid >> 2;     // 0..1
  const int wn   = wid & 3;      // 0..3
  const int fr   = lane & 15;
  const int fq   = lane >> 4;

  const int swzRd = (lane & 7) << 4;                    // frag-read byte XOR
  const int lsw   = ((lane & 7) ^ (lane >> 3)) << 4;    // stage src byte offset

  // loop-carried stage source pointers (+256 B per 2-tile iteration)
  const char* sA  = (const char*)(A + (size_t)(tm + wid * 16 + (lane >> 3)) * KIN) + lsw;
  const char* sB  = (const char*)(B + (size_t)(tn + wid * 16 + (lane >> 3)) * KIN) + lsw;
  const char* sA1 = sA + (size_t)128 * KIN * 2;   // +128 rows (half 1)
  const char* sB1 = sB + (size_t)128 * KIN * 2;

  char* const smemB = (char*)&smem[0][0][0];
  char* const dstB  = smemB + wid * 2048 + lane * 16;

  // ds_read byte-bases (relative to smemB); s1 = s0 ^ 64 (exact)
  const int rA00 = (wm * 64 + fr) * 128 + ((fq << 4) ^ swzRd);  // A buf0 s0
  const int rA01 = rA00 ^ 64;
  const int rA10 = rA00 + 65536;
  const int rA11 = rA10 ^ 64;
  const int rB00 = 32768 + (wn * 32 + fr) * 128 + ((fq << 4) ^ swzRd);
  const int rB01 = rB00 ^ 64;
  const int rB10 = rB00 + 65536;
  const int rB11 = rB10 ^ 64;

  f32x4 acc[8][4] = {};
  bf16x8 af[2][4], bv0[2][2], bv1[2][2];

  auto stage2 = [&](const char* src, char* dst) {
    __builtin_amdgcn_global_load_lds(
        (const __attribute__((address_space(1))) void*)src,
        (__attribute__((address_space(3))) void*)dst, 16, 0, 0);
    __builtin_amdgcn_global_load_lds(
        (const __attribute__((address_space(1))) void*)(src + (size_t)8 * KIN * 2),
        (__attribute__((address_space(3))) void*)(dst + 1024), 16, 0, 0);
  };

#define VMW(N) asm volatile("s_waitcnt vmcnt(" #N ")" ::: "memory")
#define LKW(N) asm volatile("s_waitcnt lgkmcnt(" #N ")" ::: "memory")
#define SB0    __builtin_amdgcn_sched_barrier(0)
#define PRI(p) __builtin_amdgcn_s_setprio(p)

// 4 ds_read_b128: af[S][0..3] from base BASE (+ i*2048 immediates)
#define RD_A4(BASE, S)                                                         \
    _Pragma("unroll")                                                          \
    for (int i_ = 0; i_ < 4; ++i_)                                             \
      af[S][i_] = *(const bf16x8*)(smemB + (BASE) + i_ * 2048);

// 2 ds_read_b128: BV[S][0..1] from base BASE
#define RD_B2(BASE, BV, S)                                                     \
    _Pragma("unroll")                                                          \
    for (int j_ = 0; j_ < 2; ++j_)                                             \
      BV[S][j_] = *(const bf16x8*)(smemB + (BASE) + j_ * 2048);

// 8 MFMA: k-group S of quadrant (MH,NH)
#define MF8(MH, NH, BV, S)                                                     \
    _Pragma("unroll")                                                          \
    for (int i_ = 0; i_ < 4; ++i_)                                             \
      _Pragma("unroll")                                                        \
      for (int j_ = 0; j_ < 2; ++j_)                                           \
        acc[(MH) * 4 + i_][(NH) * 2 + j_] =                                    \
            __builtin_amdgcn_mfma_f32_16x16x32_bf16(                           \
                af[S][i_], BV[S][j_], acc[(MH) * 4 + i_][(NH) * 2 + j_],       \
                0, 0, 0);

  // OFF1 = byte k-offset of kt+1; OFF2 = kt+2 (relative to pointers).
  // MODE: 0 steady; 1 = kt62 (stage A1(63) only, VMW(0)@P4); 2 = kt63.
#define KTILE(BUF, OFF1, OFF2, MODE)                                           \
  {                                                                            \
    /* P1: reads A0 + B0 (s0 | s1), stage A1(kt+1)->buf^1 */                   \
    RD_A4((BUF) ? rA10 : rA00, 0) RD_B2((BUF) ? rB10 : rB00, bv0, 0)           \
    SB0;                                                                       \
    RD_A4((BUF) ? rA11 : rA01, 1) RD_B2((BUF) ? rB11 : rB01, bv0, 1)           \
    if ((MODE) <= 1) stage2(sA1 + (OFF1),                                      \
                            dstB + ((BUF) ^ 1) * 65536 + 16384);               \
    LKW(8);                                                                    \
    __builtin_amdgcn_s_barrier();                                              \
    LKW(6); SB0; PRI(1); MF8(0, 0, bv0, 0)                                     \
    LKW(0); SB0; MF8(0, 0, bv0, 1) PRI(0);                                     \
    /* P2: reads B1 (s0 | s1) */                                               \
    RD_B2(((BUF) ? rB10 : rB00) + 16384, bv1, 0)                               \
    SB0;                                                                       \
    RD_B2(((BUF) ? rB11 : rB01) + 16384, bv1, 1)                               \
    LKW(2);                                                                    \
    __builtin_amdgcn_s_barrier();                                              \
    LKW(2); SB0; PRI(1); MF8(0, 1, bv1, 0)                                     \
    LKW(0); SB0; MF8(0, 1, bv1, 1) PRI(0);                                     \
    /* P3: reads A1 (s0 | s1, overwrites af), stage A0+B0(kt+2)->buf */        \
    RD_A4(((BUF) ? rA10 : rA00) + 16384, 0)                                    \
    SB0;                                                                       \
    RD_A4(((BUF) ? rA11 : rA01) + 16384, 1)                                    \
    if ((MODE) == 0) { stage2(sA + (OFF2), dstB + (BUF) * 65536);              \
                       stage2(sB + (OFF2), dstB + (BUF) * 65536 + 32768); }    \
    LKW(4);                                                                    \
    __builtin_amdgcn_s_barrier();                                              \
    LKW(4); SB0; PRI(1); MF8(1, 1, bv1, 0)                                     \
    LKW(0); SB0; MF8(1, 1, bv1, 1) PRI(0);                                     \
    /* P4: stage B1(kt+2)->buf | the ONE vm wait | barrier | cached MFMA */    \
    if ((MODE) == 0) stage2(sB1 + (OFF2), dstB + (BUF) * 65536 + 49152);       \
    if ((MODE) == 0) { VMW(6); } else if ((MODE) == 1) { VMW(0); }             \
    __builtin_amdgcn_s_barrier();                                              \
    SB0; PRI(1); MF8(1, 0, bv0, 0) MF8(1, 0, bv0, 1) PRI(0);                   \
  }

  // Prologue: kt0 all 4 halves -> buf0, kt1's A0,B0,B1 -> buf1; VMW(6)
  // (14 outstanding -> the 8 oldest = all of kt0 landed) THEN s_barrier
  // to publish cross-wave BEFORE the first KTILE's P1 reads (r16 fix).
  stage2(sA,        dstB);                    // A0 kt0
  stage2(sB,        dstB + 32768);            // B0 kt0
  stage2(sA1,       dstB + 16384);            // A1 kt0
  stage2(sB1,       dstB + 49152);            // B1 kt0
  stage2(sA  + 128, dstB + 65536);            // A0 kt1
  stage2(sB  + 128, dstB + 65536 + 32768);    // B0 kt1
  stage2(sB1 + 128, dstB + 65536 + 49152);    // B1 kt1
  VMW(6);
  __builtin_amdgcn_s_barrier();

  for (int it = 0; it < (NT - 2) / 2; ++it) {   // tiles 0..61
    KTILE(0, 128, 256, 0)
    KTILE(1, 256, 384, 0)
    sA += 256; sB += 256; sA1 += 256; sB1 += 256;
  }
  KTILE(0, 128, 0, 1)   // kt62: stage A1(63) only, drain
  KTILE(1, 0, 0, 2)     // kt63

#undef KTILE
#undef MF8
#undef RD_B2
#undef RD_A4
#undef PRI
#undef SB0
#undef LKW
#undef VMW

  // ---- Vectorized epilogue (r20, verified) ----
  // All cross-wave LDS reads ended at the final P4 barrier (P4 MFMA is
  // register-only), so smem is reusable. Per-wave private [32][36]-f32
  // region (row stride 144 B); dwordx4 stores, 8 rows x 128 B per instr.
  __builtin_amdgcn_s_barrier();
  float* const eb = (float*)(smemB + wid * 4608);
  const int erow = lane >> 3;          // 0..7
  const int ecol = (lane & 7) * 4;     // 0,4,...,28
#pragma unroll
  for (int mh = 0; mh < 2; ++mh) {
#pragma unroll
    for (int nh = 0; nh < 2; ++nh) {
#pragma unroll
      for (int c = 0; c < 2; ++c) {
#pragma unroll
        for (int i2 = 0; i2 < 2; ++i2)
#pragma unroll
          for (int j = 0; j < 2; ++j)
#pragma unroll
            for (int rr = 0; rr < 4; ++rr)
              eb[(i2 * 16 + fq * 4 + rr) * 36 + j * 16 + fr] =
                  acc[mh * 4 + c * 2 + i2][nh * 2 + j][rr] +
                  bias[tn + wn * 32 + nh * 128 + j * 16 + fr];
        __builtin_amdgcn_s_waitcnt(0);  // lgkm drain: writes before reads
        const size_t rbase = (size_t)(tm + wm * 64 + mh * 128 + c * 32 + erow);
        float* cp = C + rbase * NOUT + tn + wn * 32 + nh * 128 + ecol;
#pragma unroll
        for (int rb = 0; rb < 4; ++rb) {
          f32x4 v = *(const f32x4*)(eb + (rb * 8 + erow) * 36 + ecol);
          *(f32x4*)(cp + (size_t)rb * 8 * NOUT) = v;
        }
        __builtin_amdgcn_s_waitcnt(0);  // reads retired before next overwrite
      }
    }
  }
}

extern "C" void kernel_launch(void* const* d_in, const int* in_sizes, int n_in,
                              void* d_out, int out_size, void* d_ws, size_t ws_size,
                              hipStream_t stream) {
  const float* x    = (const float*)d_in[0];   // [8192][4096] fp32
  const float* bias = (const float*)d_in[1];   // [4096] fp32
  const int*   seed = (const int*)d_in[2];     // [1] int
  float* y = (float*)d_out;                    // [8192][4096] fp32

  // workspace: W bf16 (32 MB) | x bf16 (64 MB) — 96 MB, proven available
  uint16_t* Wb = (uint16_t*)d_ws;
  uint16_t* Xb = Wb + (size_t)NOUT * KIN;

  // prep: 8192 hydrate-groups + 16384 convert-groups, interleaved 1:2
  prep_kernel<<<24576, 256, 0, stream>>>(x, Xb, Wb, seed);

  const int grid = (TOKENS / BM) * (NOUT / BN);   // 512
  gemm_bias_kernel<<<grid, 512, 0, stream>>>(Xb, Wb, bias, y);
}

// Round 22
// 247.684 us; speedup vs baseline: 1.0456x; 1.0073x over previous
//
#include <hip/hip_runtime.h>
#include <hip/hip_bf16.h>
#include <stdint.h>

#define TOKENS 8192
#define NOUT   4096
#define KIN    4096

#define BM 256
#define BN 256
#define BK 64
#define NT (KIN / BK)   // 64 K-tiles

typedef __attribute__((ext_vector_type(8))) short bf16x8;
typedef __attribute__((ext_vector_type(4))) float f32x4;

__device__ __forceinline__ uint32_t rotl32(uint32_t x, int r) {
  return (x << r) | (x >> (32 - r));
}

__device__ __forceinline__ uint16_t f2bf_rne(float f) {
  uint32_t u = __float_as_uint(f);
  u += 0x7FFFu + ((u >> 16) & 1u);
  return (uint16_t)(u >> 16);
}

// Threefry-2x32, 20 rounds — JAX PRNG core.
__device__ __forceinline__ void threefry2x32(uint32_t k0, uint32_t k1,
                                             uint32_t c0, uint32_t c1,
                                             uint32_t& o0, uint32_t& o1) {
  uint32_t ks2 = 0x1BD11BDAu ^ k0 ^ k1;
  uint32_t x0 = c0 + k0;
  uint32_t x1 = c1 + k1;
#define TFR(r) { x0 += x1; x1 = rotl32(x1, (r)); x1 ^= x0; }
  TFR(13) TFR(15) TFR(26) TFR(6)
  x0 += k1;  x1 += ks2 + 1u;
  TFR(17) TFR(29) TFR(16) TFR(24)
  x0 += ks2; x1 += k0 + 2u;
  TFR(13) TFR(15) TFR(26) TFR(6)
  x0 += k0;  x1 += k1 + 3u;
  TFR(17) TFR(29) TFR(16) TFR(24)
  x0 += k1;  x1 += ks2 + 4u;
  TFR(13) TFR(15) TFR(26) TFR(6)
  x0 += ks2; x1 += k0 + 5u;
#undef TFR
  o0 = x0; o1 = x1;
}

// Prep (r21-verified): hydrate 8 elems/thread (16B stores), interleave 1:2
// with convert. ROUND 22: x loads are NONTEMPORAL (read-once — stop x's
// 128 MB from evicting the Xb/Wb working set out of the Infinity Cache).
__global__ void prep_kernel(const float* __restrict__ x,
                            uint16_t* __restrict__ xb,
                            uint16_t* __restrict__ W,
                            const int* __restrict__ seed_ptr) {
  uint32_t b = blockIdx.x;
  uint32_t g = b / 3u, r = b % 3u;
  if (r == 0u) {
    // hydrate group g in [0, 8192): elements j0..j0+7
    uint32_t k1 = (uint32_t)(*seed_ptr);                  // key = (0, seed)
    uint32_t j0 = (g * 256u + threadIdx.x) * 8u;          // 0 .. 2^24-8
    const float scale = 0.03125f;
    const float mn    = -0.015625f;
    union { uint16_t u[8]; bf16x8 v; } rr;
#pragma unroll
    for (int e = 0; e < 8; ++e) {
      uint32_t o0, o1;
      threefry2x32(0u, k1, 0u, j0 + (uint32_t)e, o0, o1);
      uint32_t bits = o0 ^ o1;
      float f = __uint_as_float((bits >> 9) | 0x3F800000u) - 1.0f;
      float v = fmaxf(mn, f * scale + mn);
      rr.u[e] = f2bf_rne(v);
    }
    *(bf16x8*)(W + j0) = rr.v;
  } else {
    // convert group cg in [0, 16384): 8 fp32 -> 8 bf16, NT loads
    uint32_t cg = g * 2u + (r - 1u);
    uint32_t base = (cg * 256u + threadIdx.x) * 8u;
    f32x4 a = __builtin_nontemporal_load((const f32x4*)(x + base));
    f32x4 c = __builtin_nontemporal_load((const f32x4*)(x + base + 4));
    union { uint16_t u[8]; bf16x8 v; } rr;
    rr.u[0] = f2bf_rne(a[0]); rr.u[1] = f2bf_rne(a[1]);
    rr.u[2] = f2bf_rne(a[2]); rr.u[3] = f2bf_rne(a[3]);
    rr.u[4] = f2bf_rne(c[0]); rr.u[5] = f2bf_rne(c[1]);
    rr.u[6] = f2bf_rne(c[2]); rr.u[7] = f2bf_rne(c[3]);
    *(bf16x8*)(xb + base) = rr.v;
  }
}

// ---------------------------------------------------------------------------
// GEMM loop: byte-identical to r20/r21 (verified best: 4-phase single-barrier
// schedule, addressing diet, pre-barrier counted lgkm, vectorized LDS-
// transpose epilogue). ROUND 22 change: C stores are NONTEMPORAL — C is
// never re-read, so streaming it past the LLC keeps Xb+Wb (96 MB) resident
// in the 256 MB Infinity Cache (counters showed 295 MB FETCH vs 96 MB of
// inputs: the C stream was evicting the working set every pass).
// ---------------------------------------------------------------------------
__global__ __launch_bounds__(512, 2)
void gemm_bias_kernel(const uint16_t* __restrict__ A,   // x  bf16 [TOKENS][KIN]
                      const uint16_t* __restrict__ B,   // W  bf16 [NOUT][KIN]
                      const float* __restrict__ bias,
                      float* __restrict__ C) {
  __shared__ uint16_t smem[2][2][16384];   // [buf][A=0/B=1][32KB] = 128 KiB

  const int nwgn = NOUT / BN;                 // 16
  const int nwg  = (TOKENS / BM) * nwgn;      // 512 (divisible by 8)
  int bid = blockIdx.x;
  int cpx = nwg >> 3;
  int swzb = (bid & 7) * cpx + (bid >> 3);    // bijective XCD swizzle
  const int tm = (swzb / nwgn) * BM;
  const int tn = (swzb % nwgn) * BN;

  const int t    = threadIdx.x;
  const int lane = t & 63;
  const int wid  = t >> 6;       // 0..7
  const int wm   = wid >> 2;     // 0..1
  const int wn   = wid & 3;      // 0..3
  const int fr   = lane & 15;
  const int fq   = lane >> 4;

  const int swzRd = (lane & 7) << 4;                    // frag-read byte XOR
  const int lsw   = ((lane & 7) ^ (lane >> 3)) << 4;    // stage src byte offset

  // loop-carried stage source pointers (+256 B per 2-tile iteration)
  const char* sA  = (const char*)(A + (size_t)(tm + wid * 16 + (lane >> 3)) * KIN) + lsw;
  const char* sB  = (const char*)(B + (size_t)(tn + wid * 16 + (lane >> 3)) * KIN) + lsw;
  const char* sA1 = sA + (size_t)128 * KIN * 2;   // +128 rows (half 1)
  const char* sB1 = sB + (size_t)128 * KIN * 2;

  char* const smemB = (char*)&smem[0][0][0];
  char* const dstB  = smemB + wid * 2048 + lane * 16;

  // ds_read byte-bases (relative to smemB); s1 = s0 ^ 64 (exact)
  const int rA00 = (wm * 64 + fr) * 128 + ((fq << 4) ^ swzRd);  // A buf0 s0
  const int rA01 = rA00 ^ 64;
  const int rA10 = rA00 + 65536;
  const int rA11 = rA10 ^ 64;
  const int rB00 = 32768 + (wn * 32 + fr) * 128 + ((fq << 4) ^ swzRd);
  const int rB01 = rB00 ^ 64;
  const int rB10 = rB00 + 65536;
  const int rB11 = rB10 ^ 64;

  f32x4 acc[8][4] = {};
  bf16x8 af[2][4], bv0[2][2], bv1[2][2];

  auto stage2 = [&](const char* src, char* dst) {
    __builtin_amdgcn_global_load_lds(
        (const __attribute__((address_space(1))) void*)src,
        (__attribute__((address_space(3))) void*)dst, 16, 0, 0);
    __builtin_amdgcn_global_load_lds(
        (const __attribute__((address_space(1))) void*)(src + (size_t)8 * KIN * 2),
        (__attribute__((address_space(3))) void*)(dst + 1024), 16, 0, 0);
  };

#define VMW(N) asm volatile("s_waitcnt vmcnt(" #N ")" ::: "memory")
#define LKW(N) asm volatile("s_waitcnt lgkmcnt(" #N ")" ::: "memory")
#define SB0    __builtin_amdgcn_sched_barrier(0)
#define PRI(p) __builtin_amdgcn_s_setprio(p)

// 4 ds_read_b128: af[S][0..3] from base BASE (+ i*2048 immediates)
#define RD_A4(BASE, S)                                                         \
    _Pragma("unroll")                                                          \
    for (int i_ = 0; i_ < 4; ++i_)                                             \
      af[S][i_] = *(const bf16x8*)(smemB + (BASE) + i_ * 2048);

// 2 ds_read_b128: BV[S][0..1] from base BASE
#define RD_B2(BASE, BV, S)                                                     \
    _Pragma("unroll")                                                          \
    for (int j_ = 0; j_ < 2; ++j_)                                             \
      BV[S][j_] = *(const bf16x8*)(smemB + (BASE) + j_ * 2048);

// 8 MFMA: k-group S of quadrant (MH,NH)
#define MF8(MH, NH, BV, S)                                                     \
    _Pragma("unroll")                                                          \
    for (int i_ = 0; i_ < 4; ++i_)                                             \
      _Pragma("unroll")                                                        \
      for (int j_ = 0; j_ < 2; ++j_)                                           \
        acc[(MH) * 4 + i_][(NH) * 2 + j_] =                                    \
            __builtin_amdgcn_mfma_f32_16x16x32_bf16(                           \
                af[S][i_], BV[S][j_], acc[(MH) * 4 + i_][(NH) * 2 + j_],       \
                0, 0, 0);

  // OFF1 = byte k-offset of kt+1; OFF2 = kt+2 (relative to pointers).
  // MODE: 0 steady; 1 = kt62 (stage A1(63) only, VMW(0)@P4); 2 = kt63.
#define KTILE(BUF, OFF1, OFF2, MODE)                                           \
  {                                                                            \
    /* P1: reads A0 + B0 (s0 | s1), stage A1(kt+1)->buf^1 */                   \
    RD_A4((BUF) ? rA10 : rA00, 0) RD_B2((BUF) ? rB10 : rB00, bv0, 0)           \
    SB0;                                                                       \
    RD_A4((BUF) ? rA11 : rA01, 1) RD_B2((BUF) ? rB11 : rB01, bv0, 1)           \
    if ((MODE) <= 1) stage2(sA1 + (OFF1),                                      \
                            dstB + ((BUF) ^ 1) * 65536 + 16384);               \
    LKW(8);                                                                    \
    __builtin_amdgcn_s_barrier();                                              \
    LKW(6); SB0; PRI(1); MF8(0, 0, bv0, 0)                                     \
    LKW(0); SB0; MF8(0, 0, bv0, 1) PRI(0);                                     \
    /* P2: reads B1 (s0 | s1) */                                               \
    RD_B2(((BUF) ? rB10 : rB00) + 16384, bv1, 0)                               \
    SB0;                                                                       \
    RD_B2(((BUF) ? rB11 : rB01) + 16384, bv1, 1)                               \
    LKW(2);                                                                    \
    __builtin_amdgcn_s_barrier();                                              \
    LKW(2); SB0; PRI(1); MF8(0, 1, bv1, 0)                                     \
    LKW(0); SB0; MF8(0, 1, bv1, 1) PRI(0);                                     \
    /* P3: reads A1 (s0 | s1, overwrites af), stage A0+B0(kt+2)->buf */        \
    RD_A4(((BUF) ? rA10 : rA00) + 16384, 0)                                    \
    SB0;                                                                       \
    RD_A4(((BUF) ? rA11 : rA01) + 16384, 1)                                    \
    if ((MODE) == 0) { stage2(sA + (OFF2), dstB + (BUF) * 65536);              \
                       stage2(sB + (OFF2), dstB + (BUF) * 65536 + 32768); }    \
    LKW(4);                                                                    \
    __builtin_amdgcn_s_barrier();                                              \
    LKW(4); SB0; PRI(1); MF8(1, 1, bv1, 0)                                     \
    LKW(0); SB0; MF8(1, 1, bv1, 1) PRI(0);                                     \
    /* P4: stage B1(kt+2)->buf | the ONE vm wait | barrier | cached MFMA */    \
    if ((MODE) == 0) stage2(sB1 + (OFF2), dstB + (BUF) * 65536 + 49152);       \
    if ((MODE) == 0) { VMW(6); } else if ((MODE) == 1) { VMW(0); }             \
    __builtin_amdgcn_s_barrier();                                              \
    SB0; PRI(1); MF8(1, 0, bv0, 0) MF8(1, 0, bv0, 1) PRI(0);                   \
  }

  // Prologue: kt0 all 4 halves -> buf0, kt1's A0,B0,B1 -> buf1; VMW(6)
  // (14 outstanding -> the 8 oldest = all of kt0 landed) THEN s_barrier
  // to publish cross-wave BEFORE the first KTILE's P1 reads (r16 fix).
  stage2(sA,        dstB);                    // A0 kt0
  stage2(sB,        dstB + 32768);            // B0 kt0
  stage2(sA1,       dstB + 16384);            // A1 kt0
  stage2(sB1,       dstB + 49152);            // B1 kt0
  stage2(sA  + 128, dstB + 65536);            // A0 kt1
  stage2(sB  + 128, dstB + 65536 + 32768);    // B0 kt1
  stage2(sB1 + 128, dstB + 65536 + 49152);    // B1 kt1
  VMW(6);
  __builtin_amdgcn_s_barrier();

  for (int it = 0; it < (NT - 2) / 2; ++it) {   // tiles 0..61
    KTILE(0, 128, 256, 0)
    KTILE(1, 256, 384, 0)
    sA += 256; sB += 256; sA1 += 256; sB1 += 256;
  }
  KTILE(0, 128, 0, 1)   // kt62: stage A1(63) only, drain
  KTILE(1, 0, 0, 2)     // kt63

#undef KTILE
#undef MF8
#undef RD_B2
#undef RD_A4
#undef PRI
#undef SB0
#undef LKW
#undef VMW

  // ---- Vectorized epilogue (r20, verified) + NT stores (r22) ----
  __builtin_amdgcn_s_barrier();
  float* const eb = (float*)(smemB + wid * 4608);
  const int erow = lane >> 3;          // 0..7
  const int ecol = (lane & 7) * 4;     // 0,4,...,28
#pragma unroll
  for (int mh = 0; mh < 2; ++mh) {
#pragma unroll
    for (int nh = 0; nh < 2; ++nh) {
#pragma unroll
      for (int c = 0; c < 2; ++c) {
#pragma unroll
        for (int i2 = 0; i2 < 2; ++i2)
#pragma unroll
          for (int j = 0; j < 2; ++j)
#pragma unroll
            for (int rr = 0; rr < 4; ++rr)
              eb[(i2 * 16 + fq * 4 + rr) * 36 + j * 16 + fr] =
                  acc[mh * 4 + c * 2 + i2][nh * 2 + j][rr] +
                  bias[tn + wn * 32 + nh * 128 + j * 16 + fr];
        __builtin_amdgcn_s_waitcnt(0);  // lgkm drain: writes before reads
        const size_t rbase = (size_t)(tm + wm * 64 + mh * 128 + c * 32 + erow);
        float* cp = C + rbase * NOUT + tn + wn * 32 + nh * 128 + ecol;
#pragma unroll
        for (int rb = 0; rb < 4; ++rb) {
          f32x4 v = *(const f32x4*)(eb + (rb * 8 + erow) * 36 + ecol);
          __builtin_nontemporal_store(v, (f32x4*)(cp + (size_t)rb * 8 * NOUT));
        }
        __builtin_amdgcn_s_waitcnt(0);  // reads retired before next overwrite
      }
    }
  }
}

extern "C" void kernel_launch(void* const* d_in, const int* in_sizes, int n_in,
                              void* d_out, int out_size, void* d_ws, size_t ws_size,
                              hipStream_t stream) {
  const float* x    = (const float*)d_in[0];   // [8192][4096] fp32
  const float* bias = (const float*)d_in[1];   // [4096] fp32
  const int*   seed = (const int*)d_in[2];     // [1] int
  float* y = (float*)d_out;                    // [8192][4096] fp32

  // workspace: W bf16 (32 MB) | x bf16 (64 MB) — 96 MB, proven available
  uint16_t* Wb = (uint16_t*)d_ws;
  uint16_t* Xb = Wb + (size_t)NOUT * KIN;

  // prep: 8192 hydrate-groups + 16384 convert-groups, interleaved 1:2
  prep_kernel<<<24576, 256, 0, stream>>>(x, Xb, Wb, seed);

  const int grid = (TOKENS / BM) * (NOUT / BN);   // 512
  gemm_bias_kernel<<<grid, 512, 0, stream>>>(Xb, Wb, bias, y);
}